// Round 9
// baseline (149.210 us; speedup 1.0000x reference)
//
#include <hip/hip_runtime.h>

// DcorLoss: dcor(x, y) for x,y [8192,128] fp32 -> single scalar.
//
// <HaH,HbH> = sum(a_ij b_ij) - (2/n) sum_i ra_i rb_i + Sa Sb/n^2: one fused
// pass over 128x128 pair-tiles: bf16 gram (MFMA 16x16x32) -> distances ->
// f32 block-local scalar products + row/col sums, f64 per-tile spill.
// Upper triangle only; off-diag tiles doubled + transposed col-sums.
//
// R9: NO LDS STAGING. The bf16 panels (xb+yb = 4 MB) are L2/L3-resident
// (R8 FETCH: 94% cache hit), so MFMA operands are loaded straight from
// global memory (dwordx4, 16 rows x 64B contiguous segments per instr --
// fully coalesced). This removes all staging code, the swizzled layout,
// and 6 of 8 barriers: every wave is an independent latency-pipelined
// stream, and TLP hides memory latency (the mechanism that barriers were
// defeating). Epilogue (raw v_sqrt, reg-hoisted norms, butterfly row
// reduction, atomic-free RP spill) unchanged from R8.

typedef float f32x4 __attribute__((ext_vector_type(4)));
typedef __bf16 bf16x8 __attribute__((ext_vector_type(8)));

#define NR 8192
#define D 128
#define TILE 128
#define GB 64          /* NR / TILE */
#define NT 2080        /* GB*(GB+1)/2 */

// ---------------- workspace layout (bytes) ----------------
#define OFF_YB  2097152u
#define OFF_NX  4194304u
#define OFF_NY  (OFF_NX + 32768u)
#define OFF_RPX (OFF_NY + 32768u)               /* 64*64*128 f32 = 2 MB */
#define OFF_RPY (OFF_RPX + 2097152u)            /* 2 MB */
#define OFF_PP  (OFF_RPY + 2097152u)            /* 3*2080 f64 */
#define OFF_SB  (OFF_PP + 49920u)               /* 64*5 f64 */
#define WS_NEED (OFF_SB + 2560u)

__device__ __forceinline__ unsigned short bf16_rne(float f) {
    union { float f; unsigned u; } c; c.f = f;
    unsigned u = c.u;
    u += 0x7FFFu + ((u >> 16) & 1u);
    return (unsigned short)(u >> 16);
}

// One wave per row: fp32 -> bf16 (RNE), LINEAR layout + fp32 row sq-norm.
__global__ __launch_bounds__(256) void prep_kernel(
    const float* __restrict__ x, const float* __restrict__ y,
    unsigned short* __restrict__ xb, unsigned short* __restrict__ yb,
    float* __restrict__ nx, float* __restrict__ ny)
{
    int gid = blockIdx.x * 256 + threadIdx.x;
    int wave = gid >> 6;
    int lane = threadIdx.x & 63;
    const float* src; unsigned short* db; float* dn; int row;
    if (wave < NR) { src = x; db = xb; dn = nx; row = wave; }
    else           { src = y; db = yb; dn = ny; row = wave - NR; }

    const float2 v = *reinterpret_cast<const float2*>(src + (size_t)row * D + lane * 2);
    float s = v.x * v.x + v.y * v.y;
    unsigned packed = (unsigned)bf16_rne(v.x) | ((unsigned)bf16_rne(v.y) << 16);
    *reinterpret_cast<unsigned*>(db + (size_t)row * D + lane * 2) = packed;
#pragma unroll
    for (int m = 1; m < 64; m <<= 1) s += __shfl_xor(s, m);
    if (lane == 0) dn[row] = s;
}

// butterfly step S for a 16-value array reduced over the 16-lane lrow group
#define BSTEP(arr, S) {                                                    \
    const int b_ = (lrow >> (S)) & 1;                                      \
    _Pragma("unroll")                                                      \
    for (int i_ = 0; i_ < (8 >> (S)); ++i_) {                              \
        float k_ = b_ ? arr[2 * i_ + 1] : arr[2 * i_];                     \
        float s_ = b_ ? arr[2 * i_] : arr[2 * i_ + 1];                     \
        arr[i_] = k_ + __shfl_xor(s_, 1 << (S));                           \
    } }

// One 128x128 pair-tile per block, 8 waves (2 row x 4 col quadrants of
// 64x32), 4x2 frags of mfma_f32_16x16x32_bf16. Operands read directly
// from global (L2-resident); only 2 barriers per block.
__global__ __launch_bounds__(512) void dcor_main7(
    const unsigned short* __restrict__ xb, const unsigned short* __restrict__ yb,
    const float* __restrict__ nx, const float* __restrict__ ny,
    float* __restrict__ RPx, float* __restrict__ RPy,
    double* __restrict__ Pp /* [3][NT] */)
{
    // XCD-chunked swizzle (8 XCDs, NT % 8 == 0 -> bijective)
    const int t = (blockIdx.x & 7) * (NT / 8) + (blockIdx.x >> 3);
    // triangular index t -> (bi, bj), bi <= bj
    double qd = 2.0 * GB + 1.0;
    int bi = (int)((qd - sqrt(qd * qd - 8.0 * (double)t)) * 0.5);
    while (bi > 0 && bi * GB - bi * (bi - 1) / 2 > t) --bi;
    while ((bi + 1) * GB - (bi + 1) * bi / 2 <= t) ++bi;
    const int bj = bi + (t - (bi * GB - bi * (bi - 1) / 2));
    const bool diag = (bi == bj);

    __shared__ float nl[4][TILE];   // 0:x rows 1:x cols 2:y rows 3:y cols
    __shared__ float rsum[4][TILE]; // x-row, y-row, x-col, y-col
    __shared__ float pr[3][8];

    const int tid  = threadIdx.x;
    const int lane = tid & 63, wid = tid >> 6;
    const int wr = wid >> 2, wc = wid & 3;        // 2x4 wave grid
    const int lrow = lane & 15, lkb = lane >> 4;

    if (tid < TILE) {
        nl[0][tid] = nx[bi * TILE + tid];
        nl[1][tid] = nx[bj * TILE + tid];
        nl[2][tid] = ny[bi * TILE + tid];
        nl[3][tid] = ny[bj * TILE + tid];
        rsum[0][tid] = 0.f; rsum[1][tid] = 0.f;
        rsum[2][tid] = 0.f; rsum[3][tid] = 0.f;
    }
    __syncthreads();                 // B1: nl/rsum visible

    // per-thread byte offsets within a panel (row * 256B + lkb * 16B)
    int aoff[4], boff[2];
#pragma unroll
    for (int m = 0; m < 4; ++m)
        aoff[m] = (wr * 64 + m * 16 + lrow) * 256 + lkb * 16;
#pragma unroll
    for (int nf = 0; nf < 2; ++nf)
        boff[nf] = (wc * 32 + nf * 16 + lrow) * 256 + lkb * 16;

    // gram over K=128 (4 chunks of 32), operands straight from global
    auto gram = [&](const char* TiB, const char* TjB, f32x4 (&acc)[4][2]) {
#pragma unroll
        for (int kk = 0; kk < 4; ++kk) {
            const int ko = kk * 64;           // 32 bf16 = 64B per K-chunk
            bf16x8 a[4], b[2];
#pragma unroll
            for (int m = 0; m < 4; ++m)
                a[m] = *reinterpret_cast<const bf16x8*>(TiB + aoff[m] + ko);
#pragma unroll
            for (int nf = 0; nf < 2; ++nf)
                b[nf] = *reinterpret_cast<const bf16x8*>(TjB + boff[nf] + ko);
#pragma unroll
            for (int m = 0; m < 4; ++m)
#pragma unroll
                for (int nf = 0; nf < 2; ++nf)
                    acc[m][nf] = __builtin_amdgcn_mfma_f32_16x16x32_bf16(
                        a[m], b[nf], acc[m][nf], 0, 0, 0);
        }
    };

    // C frag: row = (lane>>4)*4 + r, col = lane&15. Norms in regs; raw v_sqrt.
    auto to_dist = [&](f32x4 (&acc)[4][2], const float* nRw, const float* nC) {
        const float nc0 = nC[wc * 32 + lrow];
        const float nc1 = nC[wc * 32 + 16 + lrow];
#pragma unroll
        for (int m = 0; m < 4; ++m) {
            float nr[4];
#pragma unroll
            for (int r = 0; r < 4; ++r)
                nr[r] = nRw[wr * 64 + m * 16 + lkb * 4 + r];
#pragma unroll
            for (int nf = 0; nf < 2; ++nf) {
                const float nc = nf ? nc1 : nc0;
#pragma unroll
                for (int r = 0; r < 4; ++r) {
                    float sq = nr[r] + nc - 2.f * acc[m][nf][r];
                    acc[m][nf][r] = __builtin_amdgcn_sqrtf(fmaxf(sq, 0.f));
                }
            }
        }
        if (diag) {   // only 64/2080 blocks
#pragma unroll
            for (int m = 0; m < 4; ++m)
#pragma unroll
                for (int nf = 0; nf < 2; ++nf)
#pragma unroll
                    for (int r = 0; r < 4; ++r) {
                        int row_l = wr * 64 + m * 16 + lkb * 4 + r;
                        int col_l = wc * 32 + nf * 16 + lrow;
                        if (row_l == col_l) acc[m][nf][r] = 0.f;
                    }
        }
    };

    const f32x4 fz = {0.f, 0.f, 0.f, 0.f};
    f32x4 accX[4][2], accY[4][2];
#pragma unroll
    for (int m = 0; m < 4; ++m)
#pragma unroll
        for (int nf = 0; nf < 2; ++nf) { accX[m][nf] = fz; accY[m][nf] = fz; }

    const char* TiX = (const char*)xb + (size_t)bi * TILE * 256;
    const char* TjX = (const char*)xb + (size_t)bj * TILE * 256;
    const char* TiY = (const char*)yb + (size_t)bi * TILE * 256;
    const char* TjY = (const char*)yb + (size_t)bj * TILE * 256;

    gram(TiX, TjX, accX);
    to_dist(accX, nl[0], nl[1]);     // X distances stay in f32 regs
    gram(TiY, TjY, accY);
    to_dist(accY, nl[2], nl[3]);

    // ---- combine ----
    float pxy = 0.f, pxx = 0.f, pyy = 0.f;
    float ax[16], ay[16];
    float csx[2] = {0.f, 0.f}, csy[2] = {0.f, 0.f};
#pragma unroll
    for (int j = 0; j < 16; ++j) { ax[j] = 0.f; ay[j] = 0.f; }

#pragma unroll
    for (int m = 0; m < 4; ++m)
#pragma unroll
        for (int nf = 0; nf < 2; ++nf)
#pragma unroll
            for (int r = 0; r < 4; ++r) {
                float dx = accX[m][nf][r], dy = accY[m][nf][r];
                pxy += dx * dy;
                pxx += dx * dx;
                pyy += dy * dy;
                ax[m * 4 + r] += dx;  ay[m * 4 + r] += dy;
                csx[nf] += dx;        csy[nf] += dy;
            }

    // butterfly: 15 shuffles reduce 16 values over the 16-lane lrow group;
    // lane ends holding the full sum for value j == lrow.
    BSTEP(ax, 0) BSTEP(ay, 0)
    BSTEP(ax, 1) BSTEP(ay, 1)
    BSTEP(ax, 2) BSTEP(ay, 2)
    BSTEP(ax, 3) BSTEP(ay, 3)
    {   // j = lrow -> row = (j>>2)*16 + lkb*4 + (j&3); bijective over 64 rows
        int row_l = wr * 64 + ((lrow >> 2) << 4) + (lkb << 2) + (lrow & 3);
        atomicAdd(&rsum[0][row_l], ax[0]);
        atomicAdd(&rsum[1][row_l], ay[0]);
    }
    // col sums: reduce across the 4 lkb groups
#pragma unroll
    for (int nf = 0; nf < 2; ++nf) {
        float vx = csx[nf], vy = csy[nf];
        vx += __shfl_xor(vx, 16); vx += __shfl_xor(vx, 32);
        vy += __shfl_xor(vy, 16); vy += __shfl_xor(vy, 32);
        if (lkb == 0) {
            int col_l = wc * 32 + nf * 16 + lrow;
            atomicAdd(&rsum[2][col_l], vx);
            atomicAdd(&rsum[3][col_l], vy);
        }
    }
    // scalar products: wave reduce -> per-wave slot
#pragma unroll
    for (int m = 1; m < 64; m <<= 1) {
        pxy += __shfl_xor(pxy, m);
        pxx += __shfl_xor(pxx, m);
        pyy += __shfl_xor(pyy, m);
    }
    if (lane == 0) { pr[0][wid] = pxy; pr[1][wid] = pxx; pr[2][wid] = pyy; }
    __syncthreads();                 // B2

    if (tid == 0) {
        double sxy = 0, sxx = 0, syy = 0;
#pragma unroll
        for (int w = 0; w < 8; ++w) {
            sxy += (double)pr[0][w]; sxx += (double)pr[1][w]; syy += (double)pr[2][w];
        }
        double sc = diag ? 1.0 : 2.0;
        Pp[t] = sxy * sc;
        Pp[NT + t] = sxx * sc;
        Pp[2 * NT + t] = syy * sc;
    }
    if (tid < TILE) {   // each RP slot written by exactly one block
        RPx[((size_t)bi * GB + bj) * TILE + tid] = rsum[0][tid];
        RPy[((size_t)bi * GB + bj) * TILE + tid] = rsum[1][tid];
        if (!diag) {
            RPx[((size_t)bj * GB + bi) * TILE + tid] = rsum[2][tid];
            RPy[((size_t)bj * GB + bi) * TILE + tid] = rsum[3][tid];
        }
    }
}

// Fold per-tile partials into full row sums AND the 5 row-sum scalars.
__global__ __launch_bounds__(128) void row_reduce2(
    const float* __restrict__ RPx, const float* __restrict__ RPy,
    double* __restrict__ SB /* [GB][5] */)
{
    int b = blockIdx.x, t = threadIdx.x;
    double rx = 0.0, ry = 0.0;
    for (int k = 0; k < GB; ++k) {
        rx += (double)RPx[((size_t)b * GB + k) * TILE + t];
        ry += (double)RPy[((size_t)b * GB + k) * TILE + t];
    }
    double s0 = rx, s1 = ry, s2 = rx * ry, s3 = rx * rx, s4 = ry * ry;
#pragma unroll
    for (int m = 1; m < 64; m <<= 1) {
        s0 += __shfl_xor(s0, m); s1 += __shfl_xor(s1, m);
        s2 += __shfl_xor(s2, m); s3 += __shfl_xor(s3, m);
        s4 += __shfl_xor(s4, m);
    }
    __shared__ double sb[5][2];
    int lane = t & 63, w = t >> 6;
    if (lane == 0) { sb[0][w] = s0; sb[1][w] = s1; sb[2][w] = s2; sb[3][w] = s3; sb[4][w] = s4; }
    __syncthreads();
    if (t == 0)
#pragma unroll
        for (int i = 0; i < 5; ++i) SB[b * 5 + i] = sb[i][0] + sb[i][1];
}

__global__ __launch_bounds__(256) void dcor_final3(
    const double* __restrict__ SB, const double* __restrict__ Pp,
    unsigned* __restrict__ out)
{
    double sx = 0, sy = 0, sxy = 0, sxx = 0, syy = 0, pxy = 0, pxx = 0, pyy = 0;
    for (int b = threadIdx.x; b < GB; b += 256) {
        sx += SB[b * 5]; sy += SB[b * 5 + 1]; sxy += SB[b * 5 + 2];
        sxx += SB[b * 5 + 3]; syy += SB[b * 5 + 4];
    }
    for (int b = threadIdx.x; b < NT; b += 256) {
        pxy += Pp[b]; pxx += Pp[NT + b]; pyy += Pp[2 * NT + b];
    }
    __shared__ double red[8][4];
    int lane = threadIdx.x & 63, w = threadIdx.x >> 6;
#pragma unroll
    for (int m = 1; m < 64; m <<= 1) {
        sx += __shfl_xor(sx, m);  sy += __shfl_xor(sy, m);
        sxy += __shfl_xor(sxy, m); sxx += __shfl_xor(sxx, m); syy += __shfl_xor(syy, m);
        pxy += __shfl_xor(pxy, m); pxx += __shfl_xor(pxx, m); pyy += __shfl_xor(pyy, m);
    }
    if (lane == 0) {
        red[0][w] = sx;  red[1][w] = sy;  red[2][w] = sxy; red[3][w] = sxx;
        red[4][w] = syy; red[5][w] = pxy; red[6][w] = pxx; red[7][w] = pyy;
    }
    __syncthreads();
    if (threadIdx.x == 0) {
        sx  = red[0][0] + red[0][1] + red[0][2] + red[0][3];
        sy  = red[1][0] + red[1][1] + red[1][2] + red[1][3];
        sxy = red[2][0] + red[2][1] + red[2][2] + red[2][3];
        sxx = red[3][0] + red[3][1] + red[3][2] + red[3][3];
        syy = red[4][0] + red[4][1] + red[4][2] + red[4][3];
        pxy = red[5][0] + red[5][1] + red[5][2] + red[5][3];
        pxx = red[6][0] + red[6][1] + red[6][2] + red[6][3];
        pyy = red[7][0] + red[7][1] + red[7][2] + red[7][3];
        const double inv = 1.0 / (double)NR;
        double vxy = pxy - 2.0 * inv * sxy + sx * sy * inv * inv;
        double vxx = pxx - 2.0 * inv * sxx + sx * sx * inv * inv;
        double vyy = pyy - 2.0 * inv * syy + sy * sy * inv * inv;
        vxy = fmax(vxy, 0.0);
        vxx = fmax(vxx, 1e-30); vyy = fmax(vyy, 1e-30);
        double dcor = -sqrt(vxy) / sqrt(sqrt(vxx) * sqrt(vyy));
        unsigned short b = bf16_rne((float)dcor);
        out[0] = ((unsigned)b << 16) | (unsigned)b;   // f32-and-bf16 valid
    }
}

extern "C" void kernel_launch(void* const* d_in, const int* in_sizes, int n_in,
                              void* d_out, int out_size, void* d_ws, size_t ws_size,
                              hipStream_t stream)
{
    const float* x = (const float*)d_in[0];
    const float* y = (const float*)d_in[1];
    char* ws = (char*)d_ws;
    unsigned short* xb = (unsigned short*)(ws);
    unsigned short* yb = (unsigned short*)(ws + OFF_YB);
    float* nx = (float*)(ws + OFF_NX);
    float* ny = (float*)(ws + OFF_NY);
    float* RPx = (float*)(ws + OFF_RPX);
    float* RPy = (float*)(ws + OFF_RPY);
    double* Pp = (double*)(ws + OFF_PP);
    double* SB = (double*)(ws + OFF_SB);

    prep_kernel<<<4096, 256, 0, stream>>>(x, y, xb, yb, nx, ny);
    dcor_main7<<<NT, 512, 0, stream>>>(xb, yb, nx, ny, RPx, RPy, Pp);
    row_reduce2<<<GB, 128, 0, stream>>>(RPx, RPy, SB);
    dcor_final3<<<1, 256, 0, stream>>>(SB, Pp, (unsigned*)d_out);
}

// Round 10
// 100.073 us; speedup vs baseline: 1.4910x; 1.4910x over previous
//
#include <hip/hip_runtime.h>

// DcorLoss: dcor(x, y) for x,y [8192,128] fp32 -> single scalar.
//
// <HaH,HbH> = sum(a_ij b_ij) - (2/n) sum_i ra_i rb_i + Sa Sb/n^2: one fused
// pass over 128x128 pair-tiles: bf16 gram (MFMA 16x16x32) -> distances ->
// f32 block-local scalar products + row/col sums, f64 per-tile spill.
// Upper triangle only; off-diag tiles doubled + transposed col-sums.
//
// R10: R8 dataflow, re-tiled for residency. BK=32 K-chunks with INTERLEAVED
// LDS rows (128B = Ti-row 64B | Tj-row 64B): buffers 64->32 KB, ~37 KB
// total -> 3 blocks/CU resident (was 2) so barrier drains overlap across
// blocks. The XOR bank-swizzle moved from prep (global pre-swizzle) into
// the stage's per-lane GLOBAL address (global_load_lds source is per-lane;
// dest stays linear): slot = chunk ^ (row&7). prep is linear again. Every
// DMA issue rides under a gram (9 short phases); gram addressing is 6
// precomputed byte offsets. Epilogue (raw v_sqrt, reg norms, butterfly
// reduction, atomic-free RP spill) unchanged from R8.

typedef float f32x4 __attribute__((ext_vector_type(4)));
typedef __bf16 bf16x8 __attribute__((ext_vector_type(8)));

#define NR 8192
#define D 128
#define TILE 128
#define GB 64          /* NR / TILE */
#define NT 2080        /* GB*(GB+1)/2 */

// ---------------- workspace layout (bytes) ----------------
#define OFF_YB  2097152u
#define OFF_NX  4194304u
#define OFF_NY  (OFF_NX + 32768u)
#define OFF_RPX (OFF_NY + 32768u)               /* 64*64*128 f32 = 2 MB */
#define OFF_RPY (OFF_RPX + 2097152u)            /* 2 MB */
#define OFF_PP  (OFF_RPY + 2097152u)            /* 3*2080 f64 */
#define OFF_SB  (OFF_PP + 49920u)               /* 64*5 f64 */
#define WS_NEED (OFF_SB + 2560u)

#define GLOAD_LDS16(g, l)                                                  \
    __builtin_amdgcn_global_load_lds(                                      \
        (const __attribute__((address_space(1))) unsigned*)(g),            \
        (__attribute__((address_space(3))) unsigned*)(l), 16, 0, 0)

__device__ __forceinline__ unsigned short bf16_rne(float f) {
    union { float f; unsigned u; } c; c.f = f;
    unsigned u = c.u;
    u += 0x7FFFu + ((u >> 16) & 1u);
    return (unsigned short)(u >> 16);
}

// One wave per row: fp32 -> bf16 (RNE), LINEAR layout + fp32 row sq-norm.
__global__ __launch_bounds__(256) void prep_kernel(
    const float* __restrict__ x, const float* __restrict__ y,
    unsigned short* __restrict__ xb, unsigned short* __restrict__ yb,
    float* __restrict__ nx, float* __restrict__ ny)
{
    int gid = blockIdx.x * 256 + threadIdx.x;
    int wave = gid >> 6;
    int lane = threadIdx.x & 63;
    const float* src; unsigned short* db; float* dn; int row;
    if (wave < NR) { src = x; db = xb; dn = nx; row = wave; }
    else           { src = y; db = yb; dn = ny; row = wave - NR; }

    const float2 v = *reinterpret_cast<const float2*>(src + (size_t)row * D + lane * 2);
    float s = v.x * v.x + v.y * v.y;
    unsigned packed = (unsigned)bf16_rne(v.x) | ((unsigned)bf16_rne(v.y) << 16);
    *reinterpret_cast<unsigned*>(db + (size_t)row * D + lane * 2) = packed;
#pragma unroll
    for (int m = 1; m < 64; m <<= 1) s += __shfl_xor(s, m);
    if (lane == 0) dn[row] = s;
}

// butterfly step S for a 16-value array reduced over the 16-lane lrow group
#define BSTEP(arr, S) {                                                    \
    const int b_ = (lrow >> (S)) & 1;                                      \
    _Pragma("unroll")                                                      \
    for (int i_ = 0; i_ < (8 >> (S)); ++i_) {                              \
        float k_ = b_ ? arr[2 * i_ + 1] : arr[2 * i_];                     \
        float s_ = b_ ? arr[2 * i_] : arr[2 * i_ + 1];                     \
        arr[i_] = k_ + __shfl_xor(s_, 1 << (S));                           \
    } }

// One 128x128 pair-tile per block, 8 waves (2 row x 4 col quadrants of
// 64x32), 4x2 frags of mfma_f32_16x16x32_bf16. K=128 in 4 chunks of 32,
// double-buffered 16KB interleaved Ti|Tj LDS buffers.
__global__ __launch_bounds__(512) void dcor_main8(
    const unsigned short* __restrict__ xb, const unsigned short* __restrict__ yb,
    const float* __restrict__ nx, const float* __restrict__ ny,
    float* __restrict__ RPx, float* __restrict__ RPy,
    double* __restrict__ Pp /* [3][NT] */)
{
    // XCD-chunked swizzle (8 XCDs, NT % 8 == 0 -> bijective)
    const int t = (blockIdx.x & 7) * (NT / 8) + (blockIdx.x >> 3);
    // triangular index t -> (bi, bj), bi <= bj
    double qd = 2.0 * GB + 1.0;
    int bi = (int)((qd - sqrt(qd * qd - 8.0 * (double)t)) * 0.5);
    while (bi > 0 && bi * GB - bi * (bi - 1) / 2 > t) --bi;
    while ((bi + 1) * GB - (bi + 1) * bi / 2 <= t) ++bi;
    const int bj = bi + (t - (bi * GB - bi * (bi - 1) / 2));
    const bool diag = (bi == bj);

    // LDS row = 128B: Ti-row 64B (slots 0-3) | Tj-row 64B (slots 4-7).
    // slot = logical_chunk ^ (row&7): per 16-lane read phase the 8 slot
    // windows cover all 32 banks; rows +-8 alias 2-way (free).
    __shared__ __align__(16) unsigned short Buf[2][TILE][64];
    __shared__ float nl[4][TILE];   // 0:x rows 1:x cols 2:y rows 3:y cols
    __shared__ float rsum[4][TILE]; // x-row, y-row, x-col, y-col
    __shared__ float pr[3][8];

    const int tid  = threadIdx.x;
    const int lane = tid & 63, wid = tid >> 6;
    const int wr = wid >> 2, wc = wid & 3;        // 2x4 wave grid
    const int lrow = lane & 15, lkb = lane >> 4;

    if (tid < TILE) {
        nl[0][tid] = nx[bi * TILE + tid];
        nl[1][tid] = nx[bj * TILE + tid];
        nl[2][tid] = ny[bi * TILE + tid];
        nl[3][tid] = ny[bj * TILE + tid];
        rsum[0][tid] = 0.f; rsum[1][tid] = 0.f;
        rsum[2][tid] = 0.f; rsum[3][tid] = 0.f;
    }

    // stage K-chunk kc (32 bf16) of both tiles into buffer b: 16 x 1KB
    // segments (2/wave). Lane l of segment s fills LDS byte s*1024+l*16 =
    // (row = s*8 + l/8, slot = l&7); source = logical chunk slot^(row&7).
    auto stage = [&](int b, const unsigned short* srcb, int kc) {
        const char* gb = (const char*)srcb;
#pragma unroll
        for (int it = 0; it < 2; ++it) {
            int s = wid * 2 + it;
            int row = s * 8 + (lane >> 3);
            int c = (lane & 7) ^ (row & 7);          // logical chunk 0-7
            int pr_ = (c < 4 ? bi : bj) * TILE + row;
            const char* g = gb + (size_t)pr_ * 256 + kc * 64 + (c & 3) * 16;
            GLOAD_LDS16(g, &Buf[b][s * 8][0]);
        }
    };

    // precomputed LDS byte offsets (same for every gram call)
    int abyte[4], bbyte[2];
#pragma unroll
    for (int m = 0; m < 4; ++m) {
        int r = wr * 64 + m * 16 + lrow;
        abyte[m] = r * 128 + (lkb ^ (r & 7)) * 16;
    }
#pragma unroll
    for (int nf = 0; nf < 2; ++nf) {
        int r = wc * 32 + nf * 16 + lrow;
        bbyte[nf] = r * 128 + ((4 | lkb) ^ (r & 7)) * 16;
    }

    // one K=32 chunk: 6 ds_read_b128 + 8 MFMA
    auto gram = [&](int b, f32x4 (&acc)[4][2]) {
        const char* base = (const char*)&Buf[b][0][0];
        bf16x8 a[4], bb[2];
#pragma unroll
        for (int m = 0; m < 4; ++m)
            a[m] = *reinterpret_cast<const bf16x8*>(base + abyte[m]);
#pragma unroll
        for (int nf = 0; nf < 2; ++nf)
            bb[nf] = *reinterpret_cast<const bf16x8*>(base + bbyte[nf]);
#pragma unroll
        for (int m = 0; m < 4; ++m)
#pragma unroll
            for (int nf = 0; nf < 2; ++nf)
                acc[m][nf] = __builtin_amdgcn_mfma_f32_16x16x32_bf16(
                    a[m], bb[nf], acc[m][nf], 0, 0, 0);
    };

    // C frag: row = (lane>>4)*4 + r, col = lane&15. Norms in regs; raw v_sqrt.
    auto to_dist = [&](f32x4 (&acc)[4][2], const float* nRw, const float* nC) {
        const float nc0 = nC[wc * 32 + lrow];
        const float nc1 = nC[wc * 32 + 16 + lrow];
#pragma unroll
        for (int m = 0; m < 4; ++m) {
            float nr[4];
#pragma unroll
            for (int r = 0; r < 4; ++r)
                nr[r] = nRw[wr * 64 + m * 16 + lkb * 4 + r];
#pragma unroll
            for (int nf = 0; nf < 2; ++nf) {
                const float nc = nf ? nc1 : nc0;
#pragma unroll
                for (int r = 0; r < 4; ++r) {
                    float sq = nr[r] + nc - 2.f * acc[m][nf][r];
                    acc[m][nf][r] = __builtin_amdgcn_sqrtf(fmaxf(sq, 0.f));
                }
            }
        }
        if (diag) {   // only 64/2080 blocks
#pragma unroll
            for (int m = 0; m < 4; ++m)
#pragma unroll
                for (int nf = 0; nf < 2; ++nf)
#pragma unroll
                    for (int r = 0; r < 4; ++r) {
                        int row_l = wr * 64 + m * 16 + lkb * 4 + r;
                        int col_l = wc * 32 + nf * 16 + lrow;
                        if (row_l == col_l) acc[m][nf][r] = 0.f;
                    }
        }
    };

    const f32x4 fz = {0.f, 0.f, 0.f, 0.f};
    f32x4 accX[4][2], accY[4][2];
#pragma unroll
    for (int m = 0; m < 4; ++m)
#pragma unroll
        for (int nf = 0; nf < 2; ++nf) { accX[m][nf] = fz; accY[m][nf] = fz; }

    // ---- 9-phase pipeline: every DMA issues under a gram ----
    stage(0, xb, 0);
    __syncthreads();                                  // B1
    stage(1, xb, 1); gram(0, accX);
    __syncthreads();                                  // B2
    stage(0, xb, 2); gram(1, accX);
    __syncthreads();                                  // B3
    stage(1, xb, 3); gram(0, accX);
    __syncthreads();                                  // B4
    stage(0, yb, 0); gram(1, accX);
    to_dist(accX, nl[0], nl[1]);                      // X dists in f32 regs
    __syncthreads();                                  // B5
    stage(1, yb, 1); gram(0, accY);
    __syncthreads();                                  // B6
    stage(0, yb, 2); gram(1, accY);
    __syncthreads();                                  // B7
    stage(1, yb, 3); gram(0, accY);
    __syncthreads();                                  // B8
    gram(1, accY);
    to_dist(accY, nl[2], nl[3]);

    // ---- combine ----
    float pxy = 0.f, pxx = 0.f, pyy = 0.f;
    float ax[16], ay[16];
    float csx[2] = {0.f, 0.f}, csy[2] = {0.f, 0.f};
#pragma unroll
    for (int j = 0; j < 16; ++j) { ax[j] = 0.f; ay[j] = 0.f; }

#pragma unroll
    for (int m = 0; m < 4; ++m)
#pragma unroll
        for (int nf = 0; nf < 2; ++nf)
#pragma unroll
            for (int r = 0; r < 4; ++r) {
                float dx = accX[m][nf][r], dy = accY[m][nf][r];
                pxy += dx * dy;
                pxx += dx * dx;
                pyy += dy * dy;
                ax[m * 4 + r] += dx;  ay[m * 4 + r] += dy;
                csx[nf] += dx;        csy[nf] += dy;
            }

    // butterfly: 15 shuffles reduce 16 values over the 16-lane lrow group;
    // lane ends holding the full sum for value j == lrow.
    BSTEP(ax, 0) BSTEP(ay, 0)
    BSTEP(ax, 1) BSTEP(ay, 1)
    BSTEP(ax, 2) BSTEP(ay, 2)
    BSTEP(ax, 3) BSTEP(ay, 3)
    {   // j = lrow -> row = (j>>2)*16 + lkb*4 + (j&3); bijective over 64 rows
        int row_l = wr * 64 + ((lrow >> 2) << 4) + (lkb << 2) + (lrow & 3);
        atomicAdd(&rsum[0][row_l], ax[0]);
        atomicAdd(&rsum[1][row_l], ay[0]);
    }
    // col sums: reduce across the 4 lkb groups
#pragma unroll
    for (int nf = 0; nf < 2; ++nf) {
        float vx = csx[nf], vy = csy[nf];
        vx += __shfl_xor(vx, 16); vx += __shfl_xor(vx, 32);
        vy += __shfl_xor(vy, 16); vy += __shfl_xor(vy, 32);
        if (lkb == 0) {
            int col_l = wc * 32 + nf * 16 + lrow;
            atomicAdd(&rsum[2][col_l], vx);
            atomicAdd(&rsum[3][col_l], vy);
        }
    }
    // scalar products: wave reduce -> per-wave slot
#pragma unroll
    for (int m = 1; m < 64; m <<= 1) {
        pxy += __shfl_xor(pxy, m);
        pxx += __shfl_xor(pxx, m);
        pyy += __shfl_xor(pyy, m);
    }
    if (lane == 0) { pr[0][wid] = pxy; pr[1][wid] = pxx; pr[2][wid] = pyy; }
    __syncthreads();                                  // B9

    if (tid == 0) {
        double sxy = 0, sxx = 0, syy = 0;
#pragma unroll
        for (int w = 0; w < 8; ++w) {
            sxy += (double)pr[0][w]; sxx += (double)pr[1][w]; syy += (double)pr[2][w];
        }
        double sc = diag ? 1.0 : 2.0;
        Pp[t] = sxy * sc;
        Pp[NT + t] = sxx * sc;
        Pp[2 * NT + t] = syy * sc;
    }
    if (tid < TILE) {   // each RP slot written by exactly one block
        RPx[((size_t)bi * GB + bj) * TILE + tid] = rsum[0][tid];
        RPy[((size_t)bi * GB + bj) * TILE + tid] = rsum[1][tid];
        if (!diag) {
            RPx[((size_t)bj * GB + bi) * TILE + tid] = rsum[2][tid];
            RPy[((size_t)bj * GB + bi) * TILE + tid] = rsum[3][tid];
        }
    }
}

// Fold per-tile partials into full row sums AND the 5 row-sum scalars.
__global__ __launch_bounds__(128) void row_reduce2(
    const float* __restrict__ RPx, const float* __restrict__ RPy,
    double* __restrict__ SB /* [GB][5] */)
{
    int b = blockIdx.x, t = threadIdx.x;
    double rx = 0.0, ry = 0.0;
    for (int k = 0; k < GB; ++k) {
        rx += (double)RPx[((size_t)b * GB + k) * TILE + t];
        ry += (double)RPy[((size_t)b * GB + k) * TILE + t];
    }
    double s0 = rx, s1 = ry, s2 = rx * ry, s3 = rx * rx, s4 = ry * ry;
#pragma unroll
    for (int m = 1; m < 64; m <<= 1) {
        s0 += __shfl_xor(s0, m); s1 += __shfl_xor(s1, m);
        s2 += __shfl_xor(s2, m); s3 += __shfl_xor(s3, m);
        s4 += __shfl_xor(s4, m);
    }
    __shared__ double sb[5][2];
    int lane = t & 63, w = t >> 6;
    if (lane == 0) { sb[0][w] = s0; sb[1][w] = s1; sb[2][w] = s2; sb[3][w] = s3; sb[4][w] = s4; }
    __syncthreads();
    if (t == 0)
#pragma unroll
        for (int i = 0; i < 5; ++i) SB[b * 5 + i] = sb[i][0] + sb[i][1];
}

__global__ __launch_bounds__(256) void dcor_final3(
    const double* __restrict__ SB, const double* __restrict__ Pp,
    unsigned* __restrict__ out)
{
    double sx = 0, sy = 0, sxy = 0, sxx = 0, syy = 0, pxy = 0, pxx = 0, pyy = 0;
    for (int b = threadIdx.x; b < GB; b += 256) {
        sx += SB[b * 5]; sy += SB[b * 5 + 1]; sxy += SB[b * 5 + 2];
        sxx += SB[b * 5 + 3]; syy += SB[b * 5 + 4];
    }
    for (int b = threadIdx.x; b < NT; b += 256) {
        pxy += Pp[b]; pxx += Pp[NT + b]; pyy += Pp[2 * NT + b];
    }
    __shared__ double red[8][4];
    int lane = threadIdx.x & 63, w = threadIdx.x >> 6;
#pragma unroll
    for (int m = 1; m < 64; m <<= 1) {
        sx += __shfl_xor(sx, m);  sy += __shfl_xor(sy, m);
        sxy += __shfl_xor(sxy, m); sxx += __shfl_xor(sxx, m); syy += __shfl_xor(syy, m);
        pxy += __shfl_xor(pxy, m); pxx += __shfl_xor(pxx, m); pyy += __shfl_xor(pyy, m);
    }
    if (lane == 0) {
        red[0][w] = sx;  red[1][w] = sy;  red[2][w] = sxy; red[3][w] = sxx;
        red[4][w] = syy; red[5][w] = pxy; red[6][w] = pxx; red[7][w] = pyy;
    }
    __syncthreads();
    if (threadIdx.x == 0) {
        sx  = red[0][0] + red[0][1] + red[0][2] + red[0][3];
        sy  = red[1][0] + red[1][1] + red[1][2] + red[1][3];
        sxy = red[2][0] + red[2][1] + red[2][2] + red[2][3];
        sxx = red[3][0] + red[3][1] + red[3][2] + red[3][3];
        syy = red[4][0] + red[4][1] + red[4][2] + red[4][3];
        pxy = red[5][0] + red[5][1] + red[5][2] + red[5][3];
        pxx = red[6][0] + red[6][1] + red[6][2] + red[6][3];
        pyy = red[7][0] + red[7][1] + red[7][2] + red[7][3];
        const double inv = 1.0 / (double)NR;
        double vxy = pxy - 2.0 * inv * sxy + sx * sy * inv * inv;
        double vxx = pxx - 2.0 * inv * sxx + sx * sx * inv * inv;
        double vyy = pyy - 2.0 * inv * syy + sy * sy * inv * inv;
        vxy = fmax(vxy, 0.0);
        vxx = fmax(vxx, 1e-30); vyy = fmax(vyy, 1e-30);
        double dcor = -sqrt(vxy) / sqrt(sqrt(vxx) * sqrt(vyy));
        unsigned short b = bf16_rne((float)dcor);
        out[0] = ((unsigned)b << 16) | (unsigned)b;   // f32-and-bf16 valid
    }
}

extern "C" void kernel_launch(void* const* d_in, const int* in_sizes, int n_in,
                              void* d_out, int out_size, void* d_ws, size_t ws_size,
                              hipStream_t stream)
{
    const float* x = (const float*)d_in[0];
    const float* y = (const float*)d_in[1];
    char* ws = (char*)d_ws;
    unsigned short* xb = (unsigned short*)(ws);
    unsigned short* yb = (unsigned short*)(ws + OFF_YB);
    float* nx = (float*)(ws + OFF_NX);
    float* ny = (float*)(ws + OFF_NY);
    float* RPx = (float*)(ws + OFF_RPX);
    float* RPy = (float*)(ws + OFF_RPY);
    double* Pp = (double*)(ws + OFF_PP);
    double* SB = (double*)(ws + OFF_SB);

    prep_kernel<<<4096, 256, 0, stream>>>(x, y, xb, yb, nx, ny);
    dcor_main8<<<NT, 512, 0, stream>>>(xb, yb, nx, ny, RPx, RPy, Pp);
    row_reduce2<<<GB, 128, 0, stream>>>(RPx, RPy, SB);
    dcor_final3<<<1, 256, 0, stream>>>(SB, Pp, (unsigned*)d_out);
}

// Round 11
// 93.302 us; speedup vs baseline: 1.5992x; 1.0726x over previous
//
#include <hip/hip_runtime.h>

// DcorLoss: dcor(x, y) for x,y [8192,128] fp32 -> single scalar.
//
// <HaH,HbH> = sum(a_ij b_ij) - (2/n) sum_i ra_i rb_i + Sa Sb/n^2: one fused
// pass over 128x128 pair-tiles: bf16 gram (MFMA 16x16x32) -> distances ->
// f32 block-local scalar products + row/col sums, f64 per-tile spill.
// Upper triangle only; off-diag tiles doubled + transposed col-sums.
//
// R11: COUNTED-VMCNT PIPELINE (T4). R4-R10 all used __syncthreads(), which
// compiles to s_waitcnt vmcnt(0) before s_barrier -- every "overlapped" DMA
// was drained at the next barrier, making all schedules effectively serial
// {stage, drain, gram}. Fix: 4 x 16KB buffers, prologue stages 3 chunks,
// each phase does  s_waitcnt vmcnt(4); sched_barrier; s_barrier;
// gram(cur); stage(cur+3)  -- oldest DMA waited with 4 loads still in
// flight, ~2 phases of slack per DMA (covers L2/L3 latency). Epilogue
// drains 4->2->0. Stage/gram/combine identical to R10 (verified).

typedef float f32x4 __attribute__((ext_vector_type(4)));
typedef __bf16 bf16x8 __attribute__((ext_vector_type(8)));

#define NR 8192
#define D 128
#define TILE 128
#define GB 64          /* NR / TILE */
#define NT 2080        /* GB*(GB+1)/2 */

// ---------------- workspace layout (bytes) ----------------
#define OFF_YB  2097152u
#define OFF_NX  4194304u
#define OFF_NY  (OFF_NX + 32768u)
#define OFF_RPX (OFF_NY + 32768u)               /* 64*64*128 f32 = 2 MB */
#define OFF_RPY (OFF_RPX + 2097152u)            /* 2 MB */
#define OFF_PP  (OFF_RPY + 2097152u)            /* 3*2080 f64 */
#define OFF_SB  (OFF_PP + 49920u)               /* 64*5 f64 */
#define WS_NEED (OFF_SB + 2560u)

#define GLOAD_LDS16(g, l)                                                  \
    __builtin_amdgcn_global_load_lds(                                      \
        (const __attribute__((address_space(1))) unsigned*)(g),            \
        (__attribute__((address_space(3))) unsigned*)(l), 16, 0, 0)

// counted-wait phase barrier: oldest DMAs guaranteed complete, newer ones
// stay in flight across the barrier (the whole point -- no vmcnt(0) drain)
#define PHASE_BAR(N)                                                       \
    do {                                                                   \
        asm volatile("s_waitcnt vmcnt(" #N ")" ::: "memory");              \
        __builtin_amdgcn_sched_barrier(0);                                 \
        __builtin_amdgcn_s_barrier();                                      \
    } while (0)

__device__ __forceinline__ unsigned short bf16_rne(float f) {
    union { float f; unsigned u; } c; c.f = f;
    unsigned u = c.u;
    u += 0x7FFFu + ((u >> 16) & 1u);
    return (unsigned short)(u >> 16);
}

// One wave per row: fp32 -> bf16 (RNE), LINEAR layout + fp32 row sq-norm.
__global__ __launch_bounds__(256) void prep_kernel(
    const float* __restrict__ x, const float* __restrict__ y,
    unsigned short* __restrict__ xb, unsigned short* __restrict__ yb,
    float* __restrict__ nx, float* __restrict__ ny)
{
    int gid = blockIdx.x * 256 + threadIdx.x;
    int wave = gid >> 6;
    int lane = threadIdx.x & 63;
    const float* src; unsigned short* db; float* dn; int row;
    if (wave < NR) { src = x; db = xb; dn = nx; row = wave; }
    else           { src = y; db = yb; dn = ny; row = wave - NR; }

    const float2 v = *reinterpret_cast<const float2*>(src + (size_t)row * D + lane * 2);
    float s = v.x * v.x + v.y * v.y;
    unsigned packed = (unsigned)bf16_rne(v.x) | ((unsigned)bf16_rne(v.y) << 16);
    *reinterpret_cast<unsigned*>(db + (size_t)row * D + lane * 2) = packed;
#pragma unroll
    for (int m = 1; m < 64; m <<= 1) s += __shfl_xor(s, m);
    if (lane == 0) dn[row] = s;
}

// butterfly step S for a 16-value array reduced over the 16-lane lrow group
#define BSTEP(arr, S) {                                                    \
    const int b_ = (lrow >> (S)) & 1;                                      \
    _Pragma("unroll")                                                      \
    for (int i_ = 0; i_ < (8 >> (S)); ++i_) {                              \
        float k_ = b_ ? arr[2 * i_ + 1] : arr[2 * i_];                     \
        float s_ = b_ ? arr[2 * i_] : arr[2 * i_ + 1];                     \
        arr[i_] = k_ + __shfl_xor(s_, 1 << (S));                           \
    } }

// One 128x128 pair-tile per block, 8 waves (2 row x 4 col quadrants of
// 64x32), 4x2 frags of mfma_f32_16x16x32_bf16. K=128 in 4 chunks of 32,
// 4-deep counted-vmcnt pipeline over 4 x 16KB interleaved Ti|Tj buffers.
__global__ __launch_bounds__(512) void dcor_main9(
    const unsigned short* __restrict__ xb, const unsigned short* __restrict__ yb,
    const float* __restrict__ nx, const float* __restrict__ ny,
    float* __restrict__ RPx, float* __restrict__ RPy,
    double* __restrict__ Pp /* [3][NT] */)
{
    // XCD-chunked swizzle (8 XCDs, NT % 8 == 0 -> bijective)
    const int t = (blockIdx.x & 7) * (NT / 8) + (blockIdx.x >> 3);
    // triangular index t -> (bi, bj), bi <= bj
    double qd = 2.0 * GB + 1.0;
    int bi = (int)((qd - sqrt(qd * qd - 8.0 * (double)t)) * 0.5);
    while (bi > 0 && bi * GB - bi * (bi - 1) / 2 > t) --bi;
    while ((bi + 1) * GB - (bi + 1) * bi / 2 <= t) ++bi;
    const int bj = bi + (t - (bi * GB - bi * (bi - 1) / 2));
    const bool diag = (bi == bj);

    // LDS row = 128B: Ti-row 64B (slots 0-3) | Tj-row 64B (slots 4-7).
    // slot = logical_chunk ^ (row&7): bank-conflict-free (R10: 0 conflicts).
    __shared__ __align__(16) unsigned short Buf[4][TILE][64];
    __shared__ float nl[4][TILE];   // 0:x rows 1:x cols 2:y rows 3:y cols
    __shared__ float rsum[4][TILE]; // x-row, y-row, x-col, y-col
    __shared__ float pr[3][8];

    const int tid  = threadIdx.x;
    const int lane = tid & 63, wid = tid >> 6;
    const int wr = wid >> 2, wc = wid & 3;        // 2x4 wave grid
    const int lrow = lane & 15, lkb = lane >> 4;

    if (tid < TILE) {
        nl[0][tid] = nx[bi * TILE + tid];
        nl[1][tid] = nx[bj * TILE + tid];
        nl[2][tid] = ny[bi * TILE + tid];
        nl[3][tid] = ny[bj * TILE + tid];
        rsum[0][tid] = 0.f; rsum[1][tid] = 0.f;
        rsum[2][tid] = 0.f; rsum[3][tid] = 0.f;
    }

    // stage K-chunk kc (32 bf16) of both tiles into buffer b: 16 x 1KB
    // segments (2 gload_lds per wave -> vmcnt +2). Lane l of segment s
    // fills LDS byte s*1024 + l*16 (row s*8+l/8, slot l&7); global source
    // = logical chunk (l&7)^(row&7)  (per-lane source swizzle, linear dest).
    auto stage = [&](int b, const unsigned short* srcb, int kc) {
        const char* gb = (const char*)srcb;
#pragma unroll
        for (int it = 0; it < 2; ++it) {
            int s = wid * 2 + it;
            int row = s * 8 + (lane >> 3);
            int c = (lane & 7) ^ (row & 7);          // logical chunk 0-7
            int pr_ = (c < 4 ? bi : bj) * TILE + row;
            const char* g = gb + (size_t)pr_ * 256 + kc * 64 + (c & 3) * 16;
            GLOAD_LDS16(g, &Buf[b][s * 8][0]);
        }
    };

    // precomputed LDS byte offsets (same for every gram call)
    int abyte[4], bbyte[2];
#pragma unroll
    for (int m = 0; m < 4; ++m) {
        int r = wr * 64 + m * 16 + lrow;
        abyte[m] = r * 128 + (lkb ^ (r & 7)) * 16;
    }
#pragma unroll
    for (int nf = 0; nf < 2; ++nf) {
        int r = wc * 32 + nf * 16 + lrow;
        bbyte[nf] = r * 128 + ((4 | lkb) ^ (r & 7)) * 16;
    }

    // one K=32 chunk: 6 ds_read_b128 + 8 MFMA
    auto gram = [&](int b, f32x4 (&acc)[4][2]) {
        const char* base = (const char*)&Buf[b][0][0];
        bf16x8 a[4], bb[2];
#pragma unroll
        for (int m = 0; m < 4; ++m)
            a[m] = *reinterpret_cast<const bf16x8*>(base + abyte[m]);
#pragma unroll
        for (int nf = 0; nf < 2; ++nf)
            bb[nf] = *reinterpret_cast<const bf16x8*>(base + bbyte[nf]);
#pragma unroll
        for (int m = 0; m < 4; ++m)
#pragma unroll
            for (int nf = 0; nf < 2; ++nf)
                acc[m][nf] = __builtin_amdgcn_mfma_f32_16x16x32_bf16(
                    a[m], bb[nf], acc[m][nf], 0, 0, 0);
    };

    // C frag: row = (lane>>4)*4 + r, col = lane&15. Norms in regs; raw v_sqrt.
    auto to_dist = [&](f32x4 (&acc)[4][2], const float* nRw, const float* nC) {
        const float nc0 = nC[wc * 32 + lrow];
        const float nc1 = nC[wc * 32 + 16 + lrow];
#pragma unroll
        for (int m = 0; m < 4; ++m) {
            float nr[4];
#pragma unroll
            for (int r = 0; r < 4; ++r)
                nr[r] = nRw[wr * 64 + m * 16 + lkb * 4 + r];
#pragma unroll
            for (int nf = 0; nf < 2; ++nf) {
                const float nc = nf ? nc1 : nc0;
#pragma unroll
                for (int r = 0; r < 4; ++r) {
                    float sq = nr[r] + nc - 2.f * acc[m][nf][r];
                    acc[m][nf][r] = __builtin_amdgcn_sqrtf(fmaxf(sq, 0.f));
                }
            }
        }
        if (diag) {   // only 64/2080 blocks
#pragma unroll
            for (int m = 0; m < 4; ++m)
#pragma unroll
                for (int nf = 0; nf < 2; ++nf)
#pragma unroll
                    for (int r = 0; r < 4; ++r) {
                        int row_l = wr * 64 + m * 16 + lkb * 4 + r;
                        int col_l = wc * 32 + nf * 16 + lrow;
                        if (row_l == col_l) acc[m][nf][r] = 0.f;
                    }
        }
    };

    const f32x4 fz = {0.f, 0.f, 0.f, 0.f};
    f32x4 accX[4][2], accY[4][2];
#pragma unroll
    for (int m = 0; m < 4; ++m)
#pragma unroll
        for (int nf = 0; nf < 2; ++nf) { accX[m][nf] = fz; accY[m][nf] = fz; }

    __syncthreads();            // prologue: nl/rsum visible, vmcnt uniform 0

    // ---- depth-4 counted-vmcnt pipeline (8 gram phases) ----
    // Buffer b staged at phase p is consumed at phase p+? with >=2 phases
    // of in-flight slack; each PHASE_BAR(4) retires exactly the oldest
    // buffer's 2 loads. Re-stage of a buffer is always >=1 barrier after
    // its gram (read-before-overwrite safe).
    stage(0, xb, 0); stage(1, xb, 1); stage(2, xb, 2);   // vm: 6
    PHASE_BAR(4);                            // buf0 (x0) ready
    gram(0, accX); stage(3, xb, 3);          // vm: 6
    PHASE_BAR(4);                            // buf1 (x1) ready
    gram(1, accX); stage(0, yb, 0);          // vm: 6
    PHASE_BAR(4);                            // buf2 (x2) ready
    gram(2, accX); stage(1, yb, 1);          // vm: 6
    PHASE_BAR(4);                            // buf3 (x3) ready
    gram(3, accX);
    to_dist(accX, nl[0], nl[1]);             // X dists stay in f32 regs
    stage(2, yb, 2);                         // vm: 6
    PHASE_BAR(4);                            // buf0 (y0) ready
    gram(0, accY); stage(3, yb, 3);          // vm: 6
    PHASE_BAR(4);                            // buf1 (y1) ready
    gram(1, accY);                           // vm: 4
    PHASE_BAR(2);                            // buf2 (y2) ready
    gram(2, accY);                           // vm: 2
    PHASE_BAR(0);                            // buf3 (y3) ready
    gram(3, accY);
    to_dist(accY, nl[2], nl[3]);

    // ---- combine ----
    float pxy = 0.f, pxx = 0.f, pyy = 0.f;
    float ax[16], ay[16];
    float csx[2] = {0.f, 0.f}, csy[2] = {0.f, 0.f};
#pragma unroll
    for (int j = 0; j < 16; ++j) { ax[j] = 0.f; ay[j] = 0.f; }

#pragma unroll
    for (int m = 0; m < 4; ++m)
#pragma unroll
        for (int nf = 0; nf < 2; ++nf)
#pragma unroll
            for (int r = 0; r < 4; ++r) {
                float dx = accX[m][nf][r], dy = accY[m][nf][r];
                pxy += dx * dy;
                pxx += dx * dx;
                pyy += dy * dy;
                ax[m * 4 + r] += dx;  ay[m * 4 + r] += dy;
                csx[nf] += dx;        csy[nf] += dy;
            }

    // butterfly: 15 shuffles reduce 16 values over the 16-lane lrow group;
    // lane ends holding the full sum for value j == lrow.
    BSTEP(ax, 0) BSTEP(ay, 0)
    BSTEP(ax, 1) BSTEP(ay, 1)
    BSTEP(ax, 2) BSTEP(ay, 2)
    BSTEP(ax, 3) BSTEP(ay, 3)
    {   // j = lrow -> row = (j>>2)*16 + lkb*4 + (j&3); bijective over 64 rows
        int row_l = wr * 64 + ((lrow >> 2) << 4) + (lkb << 2) + (lrow & 3);
        atomicAdd(&rsum[0][row_l], ax[0]);
        atomicAdd(&rsum[1][row_l], ay[0]);
    }
    // col sums: reduce across the 4 lkb groups
#pragma unroll
    for (int nf = 0; nf < 2; ++nf) {
        float vx = csx[nf], vy = csy[nf];
        vx += __shfl_xor(vx, 16); vx += __shfl_xor(vx, 32);
        vy += __shfl_xor(vy, 16); vy += __shfl_xor(vy, 32);
        if (lkb == 0) {
            int col_l = wc * 32 + nf * 16 + lrow;
            atomicAdd(&rsum[2][col_l], vx);
            atomicAdd(&rsum[3][col_l], vy);
        }
    }
    // scalar products: wave reduce -> per-wave slot
#pragma unroll
    for (int m = 1; m < 64; m <<= 1) {
        pxy += __shfl_xor(pxy, m);
        pxx += __shfl_xor(pxx, m);
        pyy += __shfl_xor(pyy, m);
    }
    if (lane == 0) { pr[0][wid] = pxy; pr[1][wid] = pxx; pr[2][wid] = pyy; }
    __syncthreads();                                  // final (full drain ok)

    if (tid == 0) {
        double sxy = 0, sxx = 0, syy = 0;
#pragma unroll
        for (int w = 0; w < 8; ++w) {
            sxy += (double)pr[0][w]; sxx += (double)pr[1][w]; syy += (double)pr[2][w];
        }
        double sc = diag ? 1.0 : 2.0;
        Pp[t] = sxy * sc;
        Pp[NT + t] = sxx * sc;
        Pp[2 * NT + t] = syy * sc;
    }
    if (tid < TILE) {   // each RP slot written by exactly one block
        RPx[((size_t)bi * GB + bj) * TILE + tid] = rsum[0][tid];
        RPy[((size_t)bi * GB + bj) * TILE + tid] = rsum[1][tid];
        if (!diag) {
            RPx[((size_t)bj * GB + bi) * TILE + tid] = rsum[2][tid];
            RPy[((size_t)bj * GB + bi) * TILE + tid] = rsum[3][tid];
        }
    }
}

// Fold per-tile partials into full row sums AND the 5 row-sum scalars.
__global__ __launch_bounds__(128) void row_reduce2(
    const float* __restrict__ RPx, const float* __restrict__ RPy,
    double* __restrict__ SB /* [GB][5] */)
{
    int b = blockIdx.x, t = threadIdx.x;
    double rx = 0.0, ry = 0.0;
    for (int k = 0; k < GB; ++k) {
        rx += (double)RPx[((size_t)b * GB + k) * TILE + t];
        ry += (double)RPy[((size_t)b * GB + k) * TILE + t];
    }
    double s0 = rx, s1 = ry, s2 = rx * ry, s3 = rx * rx, s4 = ry * ry;
#pragma unroll
    for (int m = 1; m < 64; m <<= 1) {
        s0 += __shfl_xor(s0, m); s1 += __shfl_xor(s1, m);
        s2 += __shfl_xor(s2, m); s3 += __shfl_xor(s3, m);
        s4 += __shfl_xor(s4, m);
    }
    __shared__ double sb[5][2];
    int lane = t & 63, w = t >> 6;
    if (lane == 0) { sb[0][w] = s0; sb[1][w] = s1; sb[2][w] = s2; sb[3][w] = s3; sb[4][w] = s4; }
    __syncthreads();
    if (t == 0)
#pragma unroll
        for (int i = 0; i < 5; ++i) SB[b * 5 + i] = sb[i][0] + sb[i][1];
}

__global__ __launch_bounds__(256) void dcor_final3(
    const double* __restrict__ SB, const double* __restrict__ Pp,
    unsigned* __restrict__ out)
{
    double sx = 0, sy = 0, sxy = 0, sxx = 0, syy = 0, pxy = 0, pxx = 0, pyy = 0;
    for (int b = threadIdx.x; b < GB; b += 256) {
        sx += SB[b * 5]; sy += SB[b * 5 + 1]; sxy += SB[b * 5 + 2];
        sxx += SB[b * 5 + 3]; syy += SB[b * 5 + 4];
    }
    for (int b = threadIdx.x; b < NT; b += 256) {
        pxy += Pp[b]; pxx += Pp[NT + b]; pyy += Pp[2 * NT + b];
    }
    __shared__ double red[8][4];
    int lane = threadIdx.x & 63, w = threadIdx.x >> 6;
#pragma unroll
    for (int m = 1; m < 64; m <<= 1) {
        sx += __shfl_xor(sx, m);  sy += __shfl_xor(sy, m);
        sxy += __shfl_xor(sxy, m); sxx += __shfl_xor(sxx, m); syy += __shfl_xor(syy, m);
        pxy += __shfl_xor(pxy, m); pxx += __shfl_xor(pxx, m); pyy += __shfl_xor(pyy, m);
    }
    if (lane == 0) {
        red[0][w] = sx;  red[1][w] = sy;  red[2][w] = sxy; red[3][w] = sxx;
        red[4][w] = syy; red[5][w] = pxy; red[6][w] = pxx; red[7][w] = pyy;
    }
    __syncthreads();
    if (threadIdx.x == 0) {
        sx  = red[0][0] + red[0][1] + red[0][2] + red[0][3];
        sy  = red[1][0] + red[1][1] + red[1][2] + red[1][3];
        sxy = red[2][0] + red[2][1] + red[2][2] + red[2][3];
        sxx = red[3][0] + red[3][1] + red[3][2] + red[3][3];
        syy = red[4][0] + red[4][1] + red[4][2] + red[4][3];
        pxy = red[5][0] + red[5][1] + red[5][2] + red[5][3];
        pxx = red[6][0] + red[6][1] + red[6][2] + red[6][3];
        pyy = red[7][0] + red[7][1] + red[7][2] + red[7][3];
        const double inv = 1.0 / (double)NR;
        double vxy = pxy - 2.0 * inv * sxy + sx * sy * inv * inv;
        double vxx = pxx - 2.0 * inv * sxx + sx * sx * inv * inv;
        double vyy = pyy - 2.0 * inv * syy + sy * sy * inv * inv;
        vxy = fmax(vxy, 0.0);
        vxx = fmax(vxx, 1e-30); vyy = fmax(vyy, 1e-30);
        double dcor = -sqrt(vxy) / sqrt(sqrt(vxx) * sqrt(vyy));
        unsigned short b = bf16_rne((float)dcor);
        out[0] = ((unsigned)b << 16) | (unsigned)b;   // f32-and-bf16 valid
    }
}

extern "C" void kernel_launch(void* const* d_in, const int* in_sizes, int n_in,
                              void* d_out, int out_size, void* d_ws, size_t ws_size,
                              hipStream_t stream)
{
    const float* x = (const float*)d_in[0];
    const float* y = (const float*)d_in[1];
    char* ws = (char*)d_ws;
    unsigned short* xb = (unsigned short*)(ws);
    unsigned short* yb = (unsigned short*)(ws + OFF_YB);
    float* nx = (float*)(ws + OFF_NX);
    float* ny = (float*)(ws + OFF_NY);
    float* RPx = (float*)(ws + OFF_RPX);
    float* RPy = (float*)(ws + OFF_RPY);
    double* Pp = (double*)(ws + OFF_PP);
    double* SB = (double*)(ws + OFF_SB);

    prep_kernel<<<4096, 256, 0, stream>>>(x, y, xb, yb, nx, ny);
    dcor_main9<<<NT, 512, 0, stream>>>(xb, yb, nx, ny, RPx, RPy, Pp);
    row_reduce2<<<GB, 128, 0, stream>>>(RPx, RPy, SB);
    dcor_final3<<<1, 256, 0, stream>>>(SB, Pp, (unsigned*)d_out);
}